// Round 1
// baseline (348.554 us; speedup 1.0000x reference)
//
#include <hip/hip_runtime.h>
#include <cstdint>
#include <cmath>

// LQE fused: DMA-staged softmax-top4 stats + folded-mean MLP + broadcast add.
// B=32, L=10000 -> 320000 anchors; 4 sides x 33 bins; k_top=4; HID=64; NC=80.
//
// R4: latency-bound fix. rocprof R3: hbm 27.5%, VALUBusy 19%, VGPR=44 ->
// the register burst collapsed; strided 528B-per-lane loads ran ~5-deep.
// Now: 64-thread/64-anchor blocks; pred tile (33.8 KB) staged by 33
// __builtin_amdgcn_global_load_lds(16B) calls -- zero VGPR cost, all 33
// in flight, global side perfectly contiguous (lane*16B). Threads then
// stream their anchor from LDS (132-float stride == 4 mod 32 banks ->
// uniform 8 accesses/bank = wave64-b128 minimum, no conflicts, no pad).
// 38.7 KB LDS -> 4 independent single-wave blocks/CU stagger DMA vs compute.

constexpr int NB   = 33;
constexpr int DPR  = 132;
constexpr int HID  = 64;
constexpr int NCLS = 80;
constexpr int APB  = 64;    // anchors per block == blockDim.x == one wave

#define AS_GLOBAL __attribute__((address_space(1)))
#define AS_LDS    __attribute__((address_space(3)))

__device__ __forceinline__ void dma16(const void* g, void* l) {
    // gptr is per-lane (each lane's own 16B); LDS dest = uniform base + lane*16.
    __builtin_amdgcn_global_load_lds((const AS_GLOBAL uint32_t*)g,
                                     (AS_LDS uint32_t*)l, 16, 0, 0);
}

__global__
__attribute__((amdgpu_flat_work_group_size(APB, APB), amdgpu_waves_per_eu(1, 4)))
void lqe_fused(
    const float* __restrict__ scores,
    const float* __restrict__ pred,
    const float* __restrict__ w1,
    const float* __restrict__ b1,
    const float* __restrict__ w2,
    const float* __restrict__ b2,
    float* __restrict__ out)
{
    __shared__ float s_pred[APB * DPR];   // 33792 B, linear (anchor-major)
    __shared__ float s_w1[HID * 16];      // folded: w1[j][5s+q] + 0.25*w1[j][5s+4]
    __shared__ float s_b1[HID];
    __shared__ float s_w2[HID];
    __shared__ float s_b2;
    __shared__ float s_q[APB];

    const int t = threadIdx.x;
    const long long ab = (long long)blockIdx.x * APB;

    // ---- async DMA: pred tile -> LDS, 33 x 1KB, all in flight, no VGPRs ----
    {
        const uint32_t* g = (const uint32_t*)pred + ab * DPR;  // block base
        uint32_t* l = (uint32_t*)s_pred;
        #pragma unroll
        for (int k = 0; k < 33; ++k)
            dma16(g + k * 256 + t * 4,   // per-lane global src (contiguous 1KB)
                  l + k * 256);          // wave-uniform LDS dst
    }

    // ---- fold weights while the DMA flies (64 rows, one per thread) ----
    {
        #pragma unroll
        for (int s = 0; s < 4; ++s) {
            float wm = 0.25f * w1[t * 20 + s * 5 + 4];
            #pragma unroll
            for (int q = 0; q < 4; ++q)
                s_w1[t * 16 + s * 4 + q] = w1[t * 20 + s * 5 + q] + wm;
        }
        s_b1[t] = b1[t];
        s_w2[t] = w2[t];
        if (t == 0) s_b2 = b2[0];
    }

    __syncthreads();   // drains vmcnt(0) (DMA done) + lgkmcnt

    // ---- streaming softmax-top4 from LDS (ds_read_b128, conflict-free) ----
    const float4* lp = (const float4*)(s_pred + t * DPR);  // 528 B stride

    float f[16];
    float e0 = 0.f, e1 = 0.f, e2 = 0.f, e3 = 0.f, sum = 0.f;

    #pragma unroll
    for (int ld = 0; ld < 33; ++ld) {
        float4 v4 = lp[ld];
        float vv[4] = {v4.x, v4.y, v4.z, v4.w};
        #pragma unroll
        for (int c = 0; c < 4; ++c) {
            const int idx = 4 * ld + c;            // compile-time
            float e = __expf(vv[c]);
            sum += e;
            // branchless top-4 insertion (exp >= 0, so 0-init == -inf)
            float n0 = fminf(e0, e);  e0 = fmaxf(e0, e);
            float n1 = fminf(e1, n0); e1 = fmaxf(e1, n0);
            float n2 = fminf(e2, n1); e2 = fmaxf(e2, n1);
            e3 = fmaxf(e3, n2);
            if (idx % NB == NB - 1) {              // side done: 32/65/98/131
                const int s = idx / NB;
                float inv = 1.0f / sum;
                f[s * 4 + 0] = e0 * inv;
                f[s * 4 + 1] = e1 * inv;
                f[s * 4 + 2] = e2 * inv;
                f[s * 4 + 3] = e3 * inv;
                e0 = e1 = e2 = e3 = 0.f; sum = 0.f;
            }
        }
    }

    // ---- MLP: h_j = relu(b1_j + f . w1eff_j); qv = b2 + h . w2 ----
    float qv = s_b2;
    #pragma unroll
    for (int j = 0; j < HID; ++j) {
        const float4* wr = (const float4*)(s_w1 + j * 16);  // uniform broadcast
        float hj = s_b1[j];
        #pragma unroll
        for (int i4 = 0; i4 < 4; ++i4) {
            float4 w = wr[i4];
            hj = fmaf(f[4 * i4 + 0], w.x, hj);
            hj = fmaf(f[4 * i4 + 1], w.y, hj);
            hj = fmaf(f[4 * i4 + 2], w.z, hj);
            hj = fmaf(f[4 * i4 + 3], w.w, hj);
        }
        hj = fmaxf(hj, 0.f);
        qv = fmaf(hj, s_w2[j], qv);
    }

    s_q[t] = qv;
    __syncthreads();

    // ---- epilogue: out = scores + quality; 20 loads issued, then 20 stores ----
    const float4* sc4 = (const float4*)(scores + ab * NCLS);
    float4*       ot4 = (float4*)(out + ab * NCLS);

    float4 v[20];
    float  q[20];
    #pragma unroll
    for (int u = 0; u < 20; ++u) {            // 20*64 = 1280 float4 / block
        const int i = u * APB + t;
        v[u] = sc4[i];                        // deep in-flight, coalesced 1KB
        q[u] = s_q[i / 20];                   // 20 float4 per anchor
    }
    #pragma unroll
    for (int u = 0; u < 20; ++u) {
        const int i = u * APB + t;
        float4 w = v[u];
        w.x += q[u]; w.y += q[u]; w.z += q[u]; w.w += q[u];
        ot4[i] = w;
    }
}

extern "C" void kernel_launch(void* const* d_in, const int* in_sizes, int n_in,
                              void* d_out, int out_size, void* d_ws, size_t ws_size,
                              hipStream_t stream) {
    const float* scores = (const float*)d_in[0];
    const float* pred   = (const float*)d_in[1];
    const float* w1     = (const float*)d_in[2];
    const float* b1     = (const float*)d_in[3];
    const float* w2     = (const float*)d_in[4];
    const float* b2     = (const float*)d_in[5];
    // d_in[6] = k_top (==4, baked in)

    int n_anchor = in_sizes[0] / NCLS;      // 320000
    int blocks   = n_anchor / APB;          // 5000, exact
    lqe_fused<<<blocks, APB, 0, stream>>>(scores, pred, w1, b1, w2, b2,
                                          (float*)d_out);
}